// Round 2
// baseline (633.765 us; speedup 1.0000x reference)
//
#include <hip/hip_runtime.h>
#include <stdint.h>

typedef unsigned short u16;
typedef unsigned int u32;
typedef unsigned long long u64;

typedef __attribute__((ext_vector_type(8))) __bf16 bf16x8;
typedef __attribute__((ext_vector_type(4))) float f32x4;

#define NROW 8192
#define DMODEL 256
#define NH 4
#define HD 64
#define LDT 72   // LDS row stride (u16 elems): 144 B = 9*16B aligned, 36 dw -> <=2-way conflicts (free)

__device__ __forceinline__ u16 f2bf(float f) {   // RNE f32 -> bf16
    u32 u = __builtin_bit_cast(u32, f);
    u += 0x7FFFu + ((u >> 16) & 1u);
    return (u16)(u >> 16);
}
__device__ __forceinline__ bf16x8 ldb8(const u16* p) {
    uint4 v = *(const uint4*)p;
    return __builtin_bit_cast(bf16x8, v);
}
__device__ __forceinline__ f32x4 mfma16(bf16x8 a, bf16x8 b, f32x4 c) {
    return __builtin_amdgcn_mfma_f32_16x16x32_bf16(a, b, c, 0, 0, 0);
}

// ---------------- kernel 0: edge (256MB int32) -> transposed bitmask (8MB) ---
// bits[nw*8192 + m]: bit i = (edge[m][nw*64+i] != 0)
__global__ __launch_bounds__(256, 4) void k_bitmask(const int* __restrict__ edge,
                                                    u64* __restrict__ bits) {
    const int lane = threadIdx.x & 63;
    const int wv = threadIdx.x >> 6;
    for (int it = 0; it < 128; ++it) {
        u32 wid = blockIdx.x * 512u + (u32)it * 4u + (u32)wv;
        u32 m = wid & 8191u;
        u32 nw = wid >> 13;
        int v = edge[(size_t)m * NROW + nw * 64u + (u32)lane];
        u64 b = __ballot(v != 0);
        if (lane == 0) bits[wid] = b;
    }
}

// ---------------- kernel 1: QKV projections (f32 in -> bf16 out) -----------
// blockIdx.y: 0-3 -> Q (scaled by 0.125*log2e), 4-7 -> K, 8-11 -> V (transposed)
__global__ __launch_bounds__(256, 2) void k_qkv(
    const float* __restrict__ x,
    const float* __restrict__ Wq, const float* __restrict__ bq,
    const float* __restrict__ Wk, const float* __restrict__ bk,
    const float* __restrict__ Wv, const float* __restrict__ bv,
    u16* __restrict__ Qo, u16* __restrict__ Ko, u16* __restrict__ Vt) {
    __shared__ __align__(16) u16 ax[128 * LDT];
    __shared__ __align__(16) u16 wt[64 * LDT];
    const int t = threadIdx.x;
    const int lane = t & 63, wv = t >> 6;
    const int q4 = lane >> 4, l15 = lane & 15;
    const int wr = wv >> 1, wc = wv & 1;
    const int row0 = blockIdx.x * 128;
    const int mat = blockIdx.y >> 2;
    const int c0 = (blockIdx.y & 3) * 64;
    const float* W = (mat == 0) ? Wq : ((mat == 1) ? Wk : Wv);
    const float* bias = (mat == 0) ? bq : ((mat == 1) ? bk : bv);

    f32x4 acc[8];
    #pragma unroll
    for (int i = 0; i < 8; ++i) acc[i] = {0.f, 0.f, 0.f, 0.f};

    for (int kk = 0; kk < DMODEL; kk += 64) {
        #pragma unroll
        for (int i = 0; i < 8; ++i) {              // stage x tile 128x64 (f32 -> bf16)
            int chunk = t + 256 * i;               // 0..2047
            int row = chunk >> 4, c4 = chunk & 15;
            f32x4 xv = *(const f32x4*)&x[(size_t)(row0 + row) * DMODEL + kk + c4 * 4];
            u32 lo = (u32)f2bf(xv[0]) | ((u32)f2bf(xv[1]) << 16);
            u32 hi = (u32)f2bf(xv[2]) | ((u32)f2bf(xv[3]) << 16);
            uint2 pk; pk.x = lo; pk.y = hi;
            *(uint2*)&ax[row * LDT + c4 * 4] = pk;
        }
        #pragma unroll
        for (int i = 0; i < 4; ++i) {              // stage W tile 64x64 transposed (f32 -> bf16)
            int chunk = t + 256 * i;               // 0..1023
            int k = chunk >> 4, n4 = chunk & 15;
            f32x4 w4 = *(const f32x4*)&W[(size_t)(kk + k) * DMODEL + c0 + n4 * 4];
            #pragma unroll
            for (int j = 0; j < 4; ++j) wt[(n4 * 4 + j) * LDT + k] = f2bf(w4[j]);
        }
        __syncthreads();
        #pragma unroll
        for (int ks = 0; ks < 2; ++ks) {
            bf16x8 xf[4], wf[2];
            #pragma unroll
            for (int it = 0; it < 4; ++it)
                xf[it] = ldb8(&ax[(wr * 64 + it * 16 + l15) * LDT + ks * 32 + q4 * 8]);
            #pragma unroll
            for (int jt = 0; jt < 2; ++jt)
                wf[jt] = ldb8(&wt[(wc * 32 + jt * 16 + l15) * LDT + ks * 32 + q4 * 8]);
            if (mat < 2) {
                #pragma unroll
                for (int it = 0; it < 4; ++it)
                    #pragma unroll
                    for (int jt = 0; jt < 2; ++jt)
                        acc[it * 2 + jt] = mfma16(xf[it], wf[jt], acc[it * 2 + jt]);
            } else {  // V: swapped operands -> D = (xW)^T, rows = feature dim
                #pragma unroll
                for (int jt = 0; jt < 2; ++jt)
                    #pragma unroll
                    for (int it = 0; it < 4; ++it)
                        acc[jt * 4 + it] = mfma16(wf[jt], xf[it], acc[jt * 4 + it]);
            }
        }
        __syncthreads();
    }

    if (mat < 2) {
        u16* out = (mat == 0) ? Qo : Ko;
        const float scale = (mat == 0) ? 0.18033688f : 1.0f;  // 0.125*log2(e) for Q
        #pragma unroll
        for (int jt = 0; jt < 2; ++jt) {
            int col = c0 + wc * 32 + jt * 16 + l15;
            float bcol = bias[col];
            #pragma unroll
            for (int it = 0; it < 4; ++it) {
                int rowb = row0 + wr * 64 + it * 16 + q4 * 4;
                f32x4 a = acc[it * 2 + jt];
                #pragma unroll
                for (int r = 0; r < 4; ++r)
                    out[(size_t)(rowb + r) * DMODEL + col] = f2bf((a[r] + bcol) * scale);
            }
        }
    } else {
        #pragma unroll
        for (int jt = 0; jt < 2; ++jt) {
            #pragma unroll
            for (int r = 0; r < 4; ++r) {
                int drow = c0 + wc * 32 + jt * 16 + q4 * 4 + r;
                float bd = bias[drow];
                #pragma unroll
                for (int it = 0; it < 4; ++it) {
                    int col = row0 + wr * 64 + it * 16 + l15;
                    Vt[(size_t)drow * NROW + col] = f2bf(acc[jt * 4 + it][r] + bd);
                }
            }
        }
    }
}

// ---------------- kernel 2: flash attention with graph mask ----------------
// 256 blocks: head = (bid>>1)&3, qtile = ((bid>>3)<<1)|(bid&1)
// 4 waves x 32 Q-rows; BN=64; no-max softmax (exp2 domain); l via ones-MFMA.
__global__ __launch_bounds__(256, 1) void k_attn(
    const u16* __restrict__ Q, const u16* __restrict__ K,
    const u16* __restrict__ Vt, const u64* __restrict__ bits,
    float* __restrict__ out) {
    __shared__ __align__(16) u16 sK[64 * LDT];
    __shared__ __align__(16) u16 sV[64 * LDT];
    __shared__ __align__(16) u16 sP[4][32 * LDT];
    __shared__ u32 sB[4][64];

    const int t = threadIdx.x;
    const int lane = t & 63, wv = t >> 6;
    const int q4 = lane >> 4, l15 = lane & 15;
    const int bid = blockIdx.x;
    const int h = (bid >> 1) & 3;
    const int qt = ((bid >> 3) << 1) | (bid & 1);
    const int n0 = qt * 128;
    const int nbase = n0 + wv * 32;
    const int nw0 = n0 >> 6;

    bf16x8 qf[2][2];
    #pragma unroll
    for (int it = 0; it < 2; ++it)
        #pragma unroll
        for (int ks = 0; ks < 2; ++ks)
            qf[it][ks] = ldb8(&Q[(size_t)(nbase + it * 16 + l15) * DMODEL + h * HD + ks * 32 + q4 * 8]);

    uint4 onesu = {0x3F803F80u, 0x3F803F80u, 0x3F803F80u, 0x3F803F80u};
    const bf16x8 ones = __builtin_bit_cast(bf16x8, onesu);

    f32x4 o[2][4];
    f32x4 lacc[2];
    #pragma unroll
    for (int it = 0; it < 2; ++it) {
        lacc[it] = {0.f, 0.f, 0.f, 0.f};
        #pragma unroll
        for (int dt = 0; dt < 4; ++dt) o[it][dt] = {0.f, 0.f, 0.f, 0.f};
    }

    for (int kt = 0; kt < 128; ++kt) {
        const int m0 = kt * 64;
        #pragma unroll
        for (int i = 0; i < 2; ++i) {              // stage K tile 64x64 (row-major)
            int chunk = t + 256 * i;
            int mm = chunk >> 3, k8 = chunk & 7;
            *(uint4*)&sK[mm * LDT + k8 * 8] =
                *(const uint4*)&K[(size_t)(m0 + mm) * DMODEL + h * HD + k8 * 8];
        }
        #pragma unroll
        for (int i = 0; i < 2; ++i) {              // stage V^T tile 64(d)x64(m)
            int chunk = t + 256 * i;
            int d = chunk >> 3, m8 = chunk & 7;
            *(uint4*)&sV[d * LDT + m8 * 8] =
                *(const uint4*)&Vt[(size_t)(h * HD + d) * NROW + m0 + m8 * 8];
        }
        if (t < 128) {                             // stage bitmask: 2 words x 64 m
            int mm = t & 63, nwh = t >> 6;
            u64 w2 = bits[(size_t)(nw0 + nwh) * NROW + m0 + mm];
            sB[nwh][mm] = (u32)w2;
            sB[2 + nwh][mm] = (u32)(w2 >> 32);
        }
        __syncthreads();

        const int bidx = (wv & 1) * 2 + (wv >> 1);
        u32 bw[4];
        #pragma unroll
        for (int tj = 0; tj < 4; ++tj) bw[tj] = sB[bidx][tj * 16 + l15];

        f32x4 s[2][4];
        #pragma unroll
        for (int it = 0; it < 2; ++it)
            #pragma unroll
            for (int tj = 0; tj < 4; ++tj) s[it][tj] = {0.f, 0.f, 0.f, 0.f};

        #pragma unroll
        for (int ks = 0; ks < 2; ++ks) {           // S = Q K^T (log2-domain)
            bf16x8 kb[4];
            #pragma unroll
            for (int tj = 0; tj < 4; ++tj)
                kb[tj] = ldb8(&sK[(tj * 16 + l15) * LDT + ks * 32 + q4 * 8]);
            #pragma unroll
            for (int it = 0; it < 2; ++it)
                #pragma unroll
                for (int tj = 0; tj < 4; ++tj)
                    s[it][tj] = mfma16(qf[it][ks], kb[tj], s[it][tj]);
        }

        #pragma unroll
        for (int it = 0; it < 2; ++it) {           // mask + exp2 + pack P -> LDS
            #pragma unroll
            for (int tj = 0; tj < 4; ++tj) {
                u32 nib = (bw[tj] >> (it * 16 + q4 * 4)) & 0xFu;
                #pragma unroll
                for (int r = 0; r < 4; ++r) {
                    float svv = (nib & (1u << r)) ? fminf(s[it][tj][r], 80.f) : -1e30f;
                    float p = __builtin_amdgcn_exp2f(svv);
                    sP[wv][(it * 16 + q4 * 4 + r) * LDT + tj * 16 + l15] =
                        (u16)(__builtin_bit_cast(u32, p) >> 16);
                }
            }
        }
        asm volatile("s_waitcnt lgkmcnt(0)" ::: "memory");  // P is wave-private

        #pragma unroll
        for (int ks = 0; ks < 2; ++ks) {           // O += P V ; l += P 1
            bf16x8 pf[2], vb[4];
            #pragma unroll
            for (int it = 0; it < 2; ++it)
                pf[it] = ldb8(&sP[wv][(it * 16 + l15) * LDT + ks * 32 + q4 * 8]);
            #pragma unroll
            for (int dt = 0; dt < 4; ++dt)
                vb[dt] = ldb8(&sV[(dt * 16 + l15) * LDT + ks * 32 + q4 * 8]);
            #pragma unroll
            for (int it = 0; it < 2; ++it) {
                #pragma unroll
                for (int dt = 0; dt < 4; ++dt)
                    o[it][dt] = mfma16(pf[it], vb[dt], o[it][dt]);
                lacc[it] = mfma16(pf[it], ones, lacc[it]);
            }
        }
        __syncthreads();
    }

    #pragma unroll
    for (int it = 0; it < 2; ++it) {
        #pragma unroll
        for (int r = 0; r < 4; ++r) {
            float inv = __builtin_amdgcn_rcpf(lacc[it][r] + 1e-30f);
            int n = nbase + it * 16 + q4 * 4 + r;
            #pragma unroll
            for (int dt = 0; dt < 4; ++dt)
                out[(size_t)n * DMODEL + h * HD + dt * 16 + l15] = o[it][dt][r] * inv;
        }
    }
}

extern "C" void kernel_launch(void* const* d_in, const int* in_sizes, int n_in,
                              void* d_out, int out_size, void* d_ws, size_t ws_size,
                              hipStream_t stream) {
    const float* x  = (const float*)d_in[0];
    const int* edge = (const int*)d_in[1];
    const float* Wq = (const float*)d_in[2];
    const float* bq = (const float*)d_in[3];
    const float* Wk = (const float*)d_in[4];
    const float* bk = (const float*)d_in[5];
    const float* Wv = (const float*)d_in[6];
    const float* bv = (const float*)d_in[7];

    char* ws = (char*)d_ws;
    u64* bits = (u64*)ws;                        //  8 MB
    u16* Qo = (u16*)(ws + (8u << 20));           //  4 MB (bf16, Q pre-scaled by 0.125*log2e)
    u16* Ko = (u16*)(ws + (12u << 20));          //  4 MB (bf16)
    u16* Vt = (u16*)(ws + (16u << 20));          //  4 MB (bf16, transposed [256][8192])
    float* out = (float*)d_out;

    hipLaunchKernelGGL(k_bitmask, dim3(2048), dim3(256), 0, stream, edge, bits);
    hipLaunchKernelGGL(k_qkv, dim3(64, 12), dim3(256), 0, stream,
                       x, Wq, bq, Wk, bk, Wv, bv, Qo, Ko, Vt);
    hipLaunchKernelGGL(k_attn, dim3(256), dim3(256), 0, stream, Qo, Ko, Vt, bits, out);
}

// Round 3
// 543.853 us; speedup vs baseline: 1.1653x; 1.1653x over previous
//
#include <hip/hip_runtime.h>
#include <stdint.h>

typedef unsigned short u16;
typedef unsigned int u32;
typedef unsigned long long u64;

typedef __attribute__((ext_vector_type(8))) __bf16 bf16x8;
typedef __attribute__((ext_vector_type(4))) float f32x4;

#define NROW 8192
#define DMODEL 256
#define HD 64
#define LDT 72   // LDS row stride (u16): 144 B = 9*16B aligned

__device__ __forceinline__ u16 f2bf(float f) {   // RNE f32 -> bf16
    u32 u = __builtin_bit_cast(u32, f);
    u += 0x7FFFu + ((u >> 16) & 1u);
    return (u16)(u >> 16);
}
__device__ __forceinline__ bf16x8 ldb8(const u16* p) {
    uint4 v = *(const uint4*)p;
    return __builtin_bit_cast(bf16x8, v);
}
__device__ __forceinline__ f32x4 mfma16(bf16x8 a, bf16x8 b, f32x4 c) {
    return __builtin_amdgcn_mfma_f32_16x16x32_bf16(a, b, c, 0, 0, 0);
}

// ---------------- kernel P: x f32->bf16 ; W f32->bf16 transposed -----------
__global__ __launch_bounds__(256) void k_prep(
    const float* __restrict__ x,
    const float* __restrict__ Wq, const float* __restrict__ Wk,
    const float* __restrict__ Wv,
    u16* __restrict__ xb, u16* __restrict__ Wt) {
    const int t = threadIdx.x;
    if (blockIdx.x < 1024) {                       // x convert: 8 elems/thread
        size_t idx = (size_t)blockIdx.x * 2048 + t * 8;
        f32x4 a = *(const f32x4*)&x[idx];
        f32x4 b = *(const f32x4*)&x[idx + 4];
        uint4 o;
        o.x = (u32)f2bf(a[0]) | ((u32)f2bf(a[1]) << 16);
        o.y = (u32)f2bf(a[2]) | ((u32)f2bf(a[3]) << 16);
        o.z = (u32)f2bf(b[0]) | ((u32)f2bf(b[1]) << 16);
        o.w = (u32)f2bf(b[2]) | ((u32)f2bf(b[3]) << 16);
        *(uint4*)&xb[idx] = o;
        return;
    }
    // W transpose: 48 blocks, 64x64 tiles
    __shared__ __align__(16) u16 lw[64 * LDT];
    int wb = blockIdx.x - 1024;
    int mat = wb >> 4, tile = wb & 15;
    int k0 = (tile >> 2) * 64, n0 = (tile & 3) * 64;
    const float* W = (mat == 0) ? Wq : ((mat == 1) ? Wk : Wv);
    #pragma unroll
    for (int i = 0; i < 4; ++i) {
        int c = t + 256 * i;
        int k = c >> 4, c4 = c & 15;
        f32x4 w4 = *(const f32x4*)&W[(size_t)(k0 + k) * DMODEL + n0 + c4 * 4];
        uint2 pk;
        pk.x = (u32)f2bf(w4[0]) | ((u32)f2bf(w4[1]) << 16);
        pk.y = (u32)f2bf(w4[2]) | ((u32)f2bf(w4[3]) << 16);
        *(uint2*)&lw[k * LDT + c4 * 4] = pk;
    }
    __syncthreads();
    #pragma unroll
    for (int i = 0; i < 2; ++i) {
        int c = t + 256 * i;
        int n = c >> 3, k8 = c & 7;
        union { uint4 u; u16 s[8]; } pk;
        #pragma unroll
        for (int j = 0; j < 8; ++j) pk.s[j] = lw[(k8 * 8 + j) * LDT + n];
        *(uint4*)&Wt[(size_t)mat * 65536 + (size_t)(n0 + n) * DMODEL + k0 + k8 * 8] = pk.u;
    }
}

// ---------------- kernel 0: edge (256MB int32) -> transposed bitmask (8MB) ---
// bits[nw*8192 + m]: bit i = (edge[m][nw*64+i] != 0). One wave per row m.
__global__ __launch_bounds__(256, 4) void k_bitmask(const int* __restrict__ edge,
                                                    u64* __restrict__ bits) {
    const int lane = threadIdx.x & 63;
    const int wv = threadIdx.x >> 6;
    const u32 m = blockIdx.x * 4u + (u32)wv;       // row
    const size_t rbase = (size_t)m * NROW;
    for (int cc = 0; cc < 32; cc += 2) {           // 2x 256-col chunks per iter
        int v[8];
        #pragma unroll
        for (int j = 0; j < 4; ++j) v[j]     = edge[rbase + cc * 256 + j * 64 + lane];
        #pragma unroll
        for (int j = 0; j < 4; ++j) v[4 + j] = edge[rbase + cc * 256 + 256 + j * 64 + lane];
        u64 b[8];
        #pragma unroll
        for (int j = 0; j < 8; ++j) b[j] = __ballot(v[j] != 0);
        if (lane == 0) {
            #pragma unroll
            for (int j = 0; j < 8; ++j) bits[(size_t)(cc * 4 + j) * NROW + m] = b[j];
        }
    }
}

// ---------------- kernel 1: QKV projections (bf16 in -> bf16 out) ----------
// blockIdx.y: 0-3 -> Q (scaled by 0.125*log2e), 4-7 -> K, 8-11 -> V (transposed)
__global__ __launch_bounds__(256, 3) void k_qkv(
    const u16* __restrict__ xb, const u16* __restrict__ Wt,
    const float* __restrict__ bq, const float* __restrict__ bk,
    const float* __restrict__ bv,
    u16* __restrict__ Qo, u16* __restrict__ Ko, u16* __restrict__ Vt) {
    __shared__ __align__(16) u16 ax[128 * LDT];
    __shared__ __align__(16) u16 wt[64 * LDT];
    const int t = threadIdx.x;
    const int lane = t & 63, wv = t >> 6;
    const int q4 = lane >> 4, l15 = lane & 15;
    const int wr = wv >> 1, wc = wv & 1;
    const int row0 = blockIdx.x * 128;
    const int mat = blockIdx.y >> 2;
    const int c0 = (blockIdx.y & 3) * 64;
    const u16* Wm = Wt + (size_t)mat * 65536;
    const float* bias = (mat == 0) ? bq : ((mat == 1) ? bk : bv);

    f32x4 acc[8];
    #pragma unroll
    for (int i = 0; i < 8; ++i) acc[i] = {0.f, 0.f, 0.f, 0.f};

    for (int kk = 0; kk < DMODEL; kk += 64) {
        #pragma unroll
        for (int i = 0; i < 4; ++i) {              // stage x tile 128x64
            int c = t + 256 * i;
            int row = c >> 3, c8 = c & 7;
            *(uint4*)&ax[row * LDT + c8 * 8] =
                *(const uint4*)&xb[(size_t)(row0 + row) * DMODEL + kk + c8 * 8];
        }
        #pragma unroll
        for (int i = 0; i < 2; ++i) {              // stage Wt tile 64(n)x64(k)
            int c = t + 256 * i;
            int n = c >> 3, c8 = c & 7;
            *(uint4*)&wt[n * LDT + c8 * 8] =
                *(const uint4*)&Wm[(size_t)(c0 + n) * DMODEL + kk + c8 * 8];
        }
        __syncthreads();
        #pragma unroll
        for (int ks = 0; ks < 2; ++ks) {
            bf16x8 xf[4], wf[2];
            #pragma unroll
            for (int it = 0; it < 4; ++it)
                xf[it] = ldb8(&ax[(wr * 64 + it * 16 + l15) * LDT + ks * 32 + q4 * 8]);
            #pragma unroll
            for (int jt = 0; jt < 2; ++jt)
                wf[jt] = ldb8(&wt[(wc * 32 + jt * 16 + l15) * LDT + ks * 32 + q4 * 8]);
            if (mat < 2) {
                #pragma unroll
                for (int it = 0; it < 4; ++it)
                    #pragma unroll
                    for (int jt = 0; jt < 2; ++jt)
                        acc[it * 2 + jt] = mfma16(xf[it], wf[jt], acc[it * 2 + jt]);
            } else {  // V: swapped operands -> D = (xW)^T
                #pragma unroll
                for (int jt = 0; jt < 2; ++jt)
                    #pragma unroll
                    for (int it = 0; it < 4; ++it)
                        acc[jt * 4 + it] = mfma16(wf[jt], xf[it], acc[jt * 4 + it]);
            }
        }
        __syncthreads();
    }

    if (mat < 2) {
        u16* out = (mat == 0) ? Qo : Ko;
        const float scale = (mat == 0) ? 0.18033688f : 1.0f;  // 0.125*log2(e)
        #pragma unroll
        for (int jt = 0; jt < 2; ++jt) {
            int col = c0 + wc * 32 + jt * 16 + l15;
            float bcol = bias[col];
            #pragma unroll
            for (int it = 0; it < 4; ++it) {
                int rowb = row0 + wr * 64 + it * 16 + q4 * 4;
                f32x4 a = acc[it * 2 + jt];
                #pragma unroll
                for (int r = 0; r < 4; ++r)
                    out[(size_t)(rowb + r) * DMODEL + col] = f2bf((a[r] + bcol) * scale);
            }
        }
    } else {
        #pragma unroll
        for (int jt = 0; jt < 2; ++jt) {
            #pragma unroll
            for (int r = 0; r < 4; ++r) {
                int drow = c0 + wc * 32 + jt * 16 + q4 * 4 + r;
                float bd = bias[drow];
                #pragma unroll
                for (int it = 0; it < 4; ++it) {
                    int col = row0 + wr * 64 + it * 16 + l15;
                    Vt[(size_t)drow * NROW + col] = f2bf(acc[jt * 4 + it][r] + bd);
                }
            }
        }
    }
}

// ---------------- kernel 2: flash attention with graph mask ----------------
// grid 512: h=(bid>>1)&3 (head per XCD-pair), qt=((bid>>3)<<1)|(bid&1) in 0..127
// BM=64 (4 waves x 16 Q-rows), BN=64; S computed TRANSPOSED (D[m][n]) so P
// packs to LDS with ds_write_b64; no-max softmax in exp2 domain; l via ones-MFMA.
// Double-buffered K/V/bits staging with register prefetch (1 barrier/iter).
__global__ __launch_bounds__(256, 2) void k_attn(
    const u16* __restrict__ Q, const u16* __restrict__ K,
    const u16* __restrict__ Vt, const u64* __restrict__ bits,
    float* __restrict__ out) {
    __shared__ __align__(16) u16 sK[2][64 * LDT];
    __shared__ __align__(16) u16 sV[2][64 * LDT];
    __shared__ __align__(16) u16 sP[4][16 * LDT];
    __shared__ __align__(16) u32 sB[2][2][64];

    const int t = threadIdx.x;
    const int lane = t & 63, w = t >> 6;
    const int q4 = lane >> 4, l15 = lane & 15;
    const int bid = blockIdx.x;
    const int h = (bid >> 1) & 3;
    const int qt = ((bid >> 3) << 1) | (bid & 1);
    const int n0 = qt * 64;
    const int half = w >> 1;
    const u32 shift = (u32)((w & 1) * 16 + l15);
    const int sr = t >> 3, sc8 = (t & 7) * 8;     // staging coords

    bf16x8 qf[2];
    #pragma unroll
    for (int ks = 0; ks < 2; ++ks)
        qf[ks] = ldb8(&Q[(size_t)(n0 + w * 16 + l15) * DMODEL + h * HD + ks * 32 + q4 * 8]);

    uint4 onesu = {0x3F803F80u, 0x3F803F80u, 0x3F803F80u, 0x3F803F80u};
    const bf16x8 ones = __builtin_bit_cast(bf16x8, onesu);

    f32x4 o[4], lacc;
    lacc = {0.f, 0.f, 0.f, 0.f};
    #pragma unroll
    for (int dt = 0; dt < 4; ++dt) o[dt] = {0.f, 0.f, 0.f, 0.f};

    uint4 rk0, rk1, rv0, rv1; uint2 rb;
    {   // prefetch + commit tile 0
        rk0 = *(const uint4*)&K[(size_t)(0 + sr) * DMODEL + h * HD + sc8];
        rk1 = *(const uint4*)&K[(size_t)(32 + sr) * DMODEL + h * HD + sc8];
        rv0 = *(const uint4*)&Vt[(size_t)(h * HD + sr) * NROW + 0 + sc8];
        rv1 = *(const uint4*)&Vt[(size_t)(h * HD + 32 + sr) * NROW + 0 + sc8];
        if (t < 64) rb = *(const uint2*)&bits[(size_t)qt * NROW + 0 + t];
        *(uint4*)&sK[0][sr * LDT + sc8] = rk0;
        *(uint4*)&sK[0][(32 + sr) * LDT + sc8] = rk1;
        *(uint4*)&sV[0][sr * LDT + sc8] = rv0;
        *(uint4*)&sV[0][(32 + sr) * LDT + sc8] = rv1;
        if (t < 64) { sB[0][0][t] = rb.x; sB[0][1][t] = rb.y; }
    }

    for (int kt = 0; kt < 128; ++kt) {
        __syncthreads();
        const int buf = kt & 1;
        if (kt < 127) {                            // issue prefetch for kt+1
            int m0 = (kt + 1) * 64;
            rk0 = *(const uint4*)&K[(size_t)(m0 + sr) * DMODEL + h * HD + sc8];
            rk1 = *(const uint4*)&K[(size_t)(m0 + 32 + sr) * DMODEL + h * HD + sc8];
            rv0 = *(const uint4*)&Vt[(size_t)(h * HD + sr) * NROW + m0 + sc8];
            rv1 = *(const uint4*)&Vt[(size_t)(h * HD + 32 + sr) * NROW + m0 + sc8];
            if (t < 64) rb = *(const uint2*)&bits[(size_t)qt * NROW + m0 + t];
        }

        f32x4 s[4];
        #pragma unroll
        for (int tj = 0; tj < 4; ++tj) s[tj] = {0.f, 0.f, 0.f, 0.f};
        #pragma unroll
        for (int ks = 0; ks < 2; ++ks) {           // S^T = K Q^T (log2 domain)
            bf16x8 kb[4];
            #pragma unroll
            for (int tj = 0; tj < 4; ++tj)
                kb[tj] = ldb8(&sK[buf][(tj * 16 + l15) * LDT + ks * 32 + q4 * 8]);
            #pragma unroll
            for (int tj = 0; tj < 4; ++tj)
                s[tj] = mfma16(kb[tj], qf[ks], s[tj]);
        }

        #pragma unroll
        for (int tj = 0; tj < 4; ++tj) {           // mask + exp2 + pack b64 -> LDS
            uint4 bw = *(const uint4*)&sB[buf][half][tj * 16 + q4 * 4];
            u32 wd[4] = {bw.x, bw.y, bw.z, bw.w};
            u32 ub[4];
            #pragma unroll
            for (int r = 0; r < 4; ++r) {
                float sv = ((wd[r] >> shift) & 1u) ? s[tj][r] : -1e30f;
                ub[r] = __builtin_bit_cast(u32, __builtin_amdgcn_exp2f(sv));
            }
            uint2 pk;
            pk.x = (ub[0] >> 16) | (ub[1] & 0xFFFF0000u);
            pk.y = (ub[2] >> 16) | (ub[3] & 0xFFFF0000u);
            *(uint2*)&sP[w][l15 * LDT + tj * 16 + q4 * 4] = pk;
        }
        asm volatile("s_waitcnt lgkmcnt(0)" ::: "memory");  // sP is wave-private

        #pragma unroll
        for (int ks = 0; ks < 2; ++ks) {           // O += P V ; l += P 1
            bf16x8 pf = ldb8(&sP[w][l15 * LDT + ks * 32 + q4 * 8]);
            bf16x8 vb[4];
            #pragma unroll
            for (int dt = 0; dt < 4; ++dt)
                vb[dt] = ldb8(&sV[buf][(dt * 16 + l15) * LDT + ks * 32 + q4 * 8]);
            #pragma unroll
            for (int dt = 0; dt < 4; ++dt)
                o[dt] = mfma16(pf, vb[dt], o[dt]);
            lacc = mfma16(pf, ones, lacc);
        }

        if (kt < 127) {                            // commit prefetched tile
            const int nb = buf ^ 1;
            *(uint4*)&sK[nb][sr * LDT + sc8] = rk0;
            *(uint4*)&sK[nb][(32 + sr) * LDT + sc8] = rk1;
            *(uint4*)&sV[nb][sr * LDT + sc8] = rv0;
            *(uint4*)&sV[nb][(32 + sr) * LDT + sc8] = rv1;
            if (t < 64) { sB[nb][0][t] = rb.x; sB[nb][1][t] = rb.y; }
        }
    }

    #pragma unroll
    for (int r = 0; r < 4; ++r) {
        float inv = __builtin_amdgcn_rcpf(lacc[r] + 1e-30f);
        int n = n0 + w * 16 + q4 * 4 + r;
        #pragma unroll
        for (int dt = 0; dt < 4; ++dt)
            out[(size_t)n * DMODEL + h * HD + dt * 16 + l15] = o[dt][r] * inv;
    }
}

extern "C" void kernel_launch(void* const* d_in, const int* in_sizes, int n_in,
                              void* d_out, int out_size, void* d_ws, size_t ws_size,
                              hipStream_t stream) {
    const float* x  = (const float*)d_in[0];
    const int* edge = (const int*)d_in[1];
    const float* Wq = (const float*)d_in[2];
    const float* bq = (const float*)d_in[3];
    const float* Wk = (const float*)d_in[4];
    const float* bk = (const float*)d_in[5];
    const float* Wv = (const float*)d_in[6];
    const float* bv = (const float*)d_in[7];

    char* ws = (char*)d_ws;
    u64* bits = (u64*)ws;                        //  8 MB
    u16* Qo  = (u16*)(ws + (8u << 20));          //  4 MB (bf16, Q pre-scaled)
    u16* Ko  = (u16*)(ws + (12u << 20));         //  4 MB (bf16)
    u16* Vt  = (u16*)(ws + (16u << 20));         //  4 MB (bf16, [256][8192])
    u16* xb  = (u16*)(ws + (20u << 20));         //  4 MB (bf16 x)
    u16* Wt  = (u16*)(ws + (24u << 20));         //  384 KB (bf16, 3x[256n][256k])
    float* out = (float*)d_out;

    hipLaunchKernelGGL(k_prep, dim3(1072), dim3(256), 0, stream, x, Wq, Wk, Wv, xb, Wt);
    hipLaunchKernelGGL(k_bitmask, dim3(2048), dim3(256), 0, stream, edge, bits);
    hipLaunchKernelGGL(k_qkv, dim3(64, 12), dim3(256), 0, stream,
                       xb, Wt, bq, bk, bv, Qo, Ko, Vt);
    hipLaunchKernelGGL(k_attn, dim3(512), dim3(256), 0, stream, Qo, Ko, Vt, bits, out);
}